// Round 1
// baseline (4260.663 us; speedup 1.0000x reference)
//
#include <hip/hip_runtime.h>
#include <hip/hip_bf16.h>

// Problem dims
#define BB 64
#define LL 512
#define DD 256
#define VV 32000
#define KK 6
#define HH 4
#define HD 64
#define FF 512
#define MM (BB * LL)   // 32768 rows

typedef __hip_bfloat16 bf16;

__device__ __forceinline__ float bflo(unsigned u) { return __uint_as_float(u << 16); }
__device__ __forceinline__ float bfhi(unsigned u) { return __uint_as_float(u & 0xffff0000u); }

// -------- block-wide reductions (256 threads = 4 waves) --------
__device__ __forceinline__ float blk_sum(float v, float* red) {
  #pragma unroll
  for (int o = 32; o > 0; o >>= 1) v += __shfl_down(v, o, 64);
  __syncthreads();
  if ((threadIdx.x & 63) == 0) red[threadIdx.x >> 6] = v;
  __syncthreads();
  return red[0] + red[1] + red[2] + red[3];
}

// -------- lengths from tokens (mask == tokens!=0, prefix mask) --------
__global__ __launch_bounds__(256) void k_lens(const int* __restrict__ tokens, int* __restrict__ lens) {
  __shared__ float red[4];
  int b = blockIdx.x, t = threadIdx.x;
  float c = (tokens[b * LL + t] != 0 ? 1.f : 0.f) + (tokens[b * LL + 256 + t] != 0 ? 1.f : 0.f);
  float s = blk_sum(c, red);
  if (t == 0) lens[b] = (int)(s + 0.5f);
}

// -------- embedding + LN -> X (f32) --------
__global__ __launch_bounds__(256) void k_embed(const int* __restrict__ tokens,
                                               const float* __restrict__ tok_emb,
                                               const float* __restrict__ pos_emb,
                                               const float* __restrict__ g,
                                               const float* __restrict__ be,
                                               float* __restrict__ X) {
  __shared__ float red[4];
  int row = blockIdx.x;           // b*L + l
  int l = row & (LL - 1);
  int t = threadIdx.x;
  int tok = tokens[row];
  float v = tok_emb[(size_t)tok * DD + t] + pos_emb[l * DD + t];
  float mu = blk_sum(v, red) * (1.f / DD);
  float c = v - mu;
  float var = blk_sum(c * c, red) * (1.f / DD);
  X[(size_t)row * DD + t] = c * rsqrtf(var + 1e-5f) * g[t] + be[t];
}

// -------- LN(X) -> bf16 H (skips invalid rows) --------
__global__ __launch_bounds__(256) void k_ln(const float* __restrict__ X,
                                            const float* __restrict__ g,
                                            const float* __restrict__ be,
                                            const int* __restrict__ lens,
                                            bf16* __restrict__ H) {
  int row = blockIdx.x;
  int l = row & (LL - 1);
  int b = row >> 9;
  if (l >= lens[b]) return;       // uniform per block
  __shared__ float red[4];
  int t = threadIdx.x;
  float v = X[(size_t)row * DD + t];
  float mu = blk_sum(v, red) * (1.f / DD);
  float c = v - mu;
  float var = blk_sum(c * c, red) * (1.f / DD);
  H[(size_t)row * DD + t] = __float2bfloat16(c * rsqrtf(var + 1e-5f) * g[t] + be[t]);
}

// -------- GEMM: out[M,N] = op(A[M,K](bf16) * W[N,K]^T + bias (+res)) --------
// 64x64 tile, BK=32, 256 threads, 4x4 micro-tile. Row-block skip via lens.
template <bool GELU, bool RES, bool OUTBF16>
__global__ __launch_bounds__(256) void k_gemm(const bf16* __restrict__ A,
                                              const float* __restrict__ W,
                                              const float* __restrict__ bias,
                                              const float* __restrict__ res,
                                              void* __restrict__ outp,
                                              const int* __restrict__ lens,
                                              int Ndim, int Kdim) {
  int n0 = blockIdx.x * 64;
  int m0 = blockIdx.y * 64;
  int b = m0 >> 9, l0 = m0 & (LL - 1);
  if (l0 >= lens[b]) return;      // uniform: whole tile is padding rows
  __shared__ float As[32][68];
  __shared__ float Bs[32][68];
  int t = threadIdx.x;
  int lr = t >> 2;                // 0..63 (row within tile)
  int lc = (t & 3) << 3;          // 0,8,16,24 (k within K-tile)
  int tx = t & 15, ty = t >> 4;
  float acc[4][4] = {};
  const bf16* Arow = A + (size_t)(m0 + lr) * Kdim + lc;
  const float* Wrow = W + (size_t)(n0 + lr) * Kdim + lc;
  for (int k0 = 0; k0 < Kdim; k0 += 32) {
    uint4 ra = *reinterpret_cast<const uint4*>(Arow + k0);
    float4 w0 = *reinterpret_cast<const float4*>(Wrow + k0);
    float4 w1 = *reinterpret_cast<const float4*>(Wrow + k0 + 4);
    As[lc + 0][lr] = bflo(ra.x); As[lc + 1][lr] = bfhi(ra.x);
    As[lc + 2][lr] = bflo(ra.y); As[lc + 3][lr] = bfhi(ra.y);
    As[lc + 4][lr] = bflo(ra.z); As[lc + 5][lr] = bfhi(ra.z);
    As[lc + 6][lr] = bflo(ra.w); As[lc + 7][lr] = bfhi(ra.w);
    Bs[lc + 0][lr] = w0.x; Bs[lc + 1][lr] = w0.y; Bs[lc + 2][lr] = w0.z; Bs[lc + 3][lr] = w0.w;
    Bs[lc + 4][lr] = w1.x; Bs[lc + 5][lr] = w1.y; Bs[lc + 6][lr] = w1.z; Bs[lc + 7][lr] = w1.w;
    __syncthreads();
    #pragma unroll
    for (int kk = 0; kk < 32; kk++) {
      float4 av = *reinterpret_cast<const float4*>(&As[kk][ty * 4]);
      float4 bv = *reinterpret_cast<const float4*>(&Bs[kk][tx * 4]);
      acc[0][0] += av.x * bv.x; acc[0][1] += av.x * bv.y; acc[0][2] += av.x * bv.z; acc[0][3] += av.x * bv.w;
      acc[1][0] += av.y * bv.x; acc[1][1] += av.y * bv.y; acc[1][2] += av.y * bv.z; acc[1][3] += av.y * bv.w;
      acc[2][0] += av.z * bv.x; acc[2][1] += av.z * bv.y; acc[2][2] += av.z * bv.z; acc[2][3] += av.z * bv.w;
      acc[3][0] += av.w * bv.x; acc[3][1] += av.w * bv.y; acc[3][2] += av.w * bv.z; acc[3][3] += av.w * bv.w;
    }
    __syncthreads();
  }
  #pragma unroll
  for (int i = 0; i < 4; i++) {
    int m = m0 + ty * 4 + i;
    #pragma unroll
    for (int j = 0; j < 4; j++) {
      int n = n0 + tx * 4 + j;
      float v = acc[i][j] + bias[n];
      if (RES) v += res[(size_t)m * Ndim + n];
      if (GELU) v = 0.5f * v * (1.f + erff(v * 0.70710678118f));
      if (OUTBF16) ((bf16*)outp)[(size_t)m * Ndim + n] = __float2bfloat16(v);
      else         ((float*)outp)[(size_t)m * Ndim + n] = v;
    }
  }
}

// -------- attention: one query per thread, online softmax, K/V tiles in LDS --------
__global__ __launch_bounds__(256) void k_attn(const bf16* __restrict__ QKV,
                                              const int* __restrict__ lens,
                                              bf16* __restrict__ O) {
  int b = blockIdx.z, h = blockIdx.y;
  int len = lens[b];
  if ((int)(blockIdx.x * 256) >= len) return;   // uniform
  int t = threadIdx.x;
  int lq = blockIdx.x * 256 + t;
  __shared__ float Ksf[64][64];
  __shared__ float Vsf[64][64];
  const bf16* base = QKV + (size_t)b * LL * (3 * DD);
  float q[64];
  const bf16* qp = base + (size_t)lq * (3 * DD) + h * HD;
  #pragma unroll
  for (int d = 0; d < 64; d += 8) {
    uint4 r = *reinterpret_cast<const uint4*>(qp + d);
    q[d + 0] = bflo(r.x); q[d + 1] = bfhi(r.x);
    q[d + 2] = bflo(r.y); q[d + 3] = bfhi(r.y);
    q[d + 4] = bflo(r.z); q[d + 5] = bfhi(r.z);
    q[d + 6] = bflo(r.w); q[d + 7] = bfhi(r.w);
  }
  float m = -1e30f, lsum = 0.f;
  float o[64] = {};
  bool active = (lq < len);
  for (int kt = 0; kt < LL; kt += 64) {
    if (kt >= len) break;          // uniform
    __syncthreads();
    #pragma unroll
    for (int j = 0; j < 4; j++) {
      int idx = j * 256 + t;
      int r = idx >> 4;            // 0..63
      int c4 = (idx & 15) << 2;    // 0..60
      const bf16* kp = base + (size_t)(kt + r) * (3 * DD) + DD + h * HD + c4;
      uint2 kw = *reinterpret_cast<const uint2*>(kp);
      uint2 vw = *reinterpret_cast<const uint2*>(kp + DD);
      Ksf[r][c4 + 0] = bflo(kw.x); Ksf[r][c4 + 1] = bfhi(kw.x);
      Ksf[r][c4 + 2] = bflo(kw.y); Ksf[r][c4 + 3] = bfhi(kw.y);
      Vsf[r][c4 + 0] = bflo(vw.x); Vsf[r][c4 + 1] = bfhi(vw.x);
      Vsf[r][c4 + 2] = bflo(vw.y); Vsf[r][c4 + 3] = bfhi(vw.y);
    }
    __syncthreads();
    if (active) {
      int kmax = min(64, len - kt);
      for (int kk = 0; kk < kmax; kk++) {
        const float4* krow = reinterpret_cast<const float4*>(&Ksf[kk][0]);
        float s0 = 0, s1 = 0, s2 = 0, s3 = 0;
        #pragma unroll
        for (int d4 = 0; d4 < 16; d4++) {
          float4 kv = krow[d4];
          s0 += q[d4 * 4 + 0] * kv.x; s1 += q[d4 * 4 + 1] * kv.y;
          s2 += q[d4 * 4 + 2] * kv.z; s3 += q[d4 * 4 + 3] * kv.w;
        }
        float s = ((s0 + s1) + (s2 + s3)) * 0.125f;
        if (s > m) {
          float corr = __expf(m - s);
          lsum *= corr;
          #pragma unroll
          for (int d = 0; d < 64; d++) o[d] *= corr;
          m = s;
        }
        float p = __expf(s - m);
        lsum += p;
        const float4* vrow = reinterpret_cast<const float4*>(&Vsf[kk][0]);
        #pragma unroll
        for (int d4 = 0; d4 < 16; d4++) {
          float4 vv = vrow[d4];
          o[d4 * 4 + 0] += p * vv.x; o[d4 * 4 + 1] += p * vv.y;
          o[d4 * 4 + 2] += p * vv.z; o[d4 * 4 + 3] += p * vv.w;
        }
      }
    }
  }
  if (active) {
    float inv = 1.f / lsum;
    bf16* op = O + (size_t)(b * LL + lq) * DD + h * HD;
    #pragma unroll
    for (int d = 0; d < 64; d++) op[d] = __float2bfloat16(o[d] * inv);
  }
}

// -------- final attention pooling: pooled[b,:] (bf16) --------
__global__ __launch_bounds__(256) void k_pool(const float* __restrict__ X,
                                              const int* __restrict__ lens,
                                              bf16* __restrict__ pooled) {
  __shared__ float red[4];
  __shared__ float qs[DD];
  __shared__ float sc[LL];
  int b = blockIdx.x, t = threadIdx.x;
  int len = lens[b];
  const float* Xb = X + (size_t)b * LL * DD;
  qs[t] = Xb[(size_t)(len - 1) * DD + t];
  __syncthreads();
  for (int l = t; l < LL; l += 256) {
    float s = -1e30f;
    if (l < len) {
      const float4* xr = reinterpret_cast<const float4*>(Xb + (size_t)l * DD);
      const float4* qq = reinterpret_cast<const float4*>(qs);
      float a0 = 0, a1 = 0, a2 = 0, a3 = 0;
      for (int k4 = 0; k4 < 64; k4++) {
        float4 xv = xr[k4], qv = qq[k4];
        a0 += xv.x * qv.x; a1 += xv.y * qv.y; a2 += xv.z * qv.z; a3 += xv.w * qv.w;
      }
      s = (a0 + a1) + (a2 + a3);
    }
    sc[l] = s;
  }
  __syncthreads();
  float mx = fmaxf(sc[t], sc[t + 256]);
  #pragma unroll
  for (int off = 32; off > 0; off >>= 1) mx = fmaxf(mx, __shfl_down(mx, off, 64));
  __syncthreads();
  if ((t & 63) == 0) red[t >> 6] = mx;
  __syncthreads();
  mx = fmaxf(fmaxf(red[0], red[1]), fmaxf(red[2], red[3]));
  float e0 = (t < len) ? __expf(sc[t] - mx) : 0.f;
  float e1 = (t + 256 < len) ? __expf(sc[t + 256] - mx) : 0.f;
  float ssum = blk_sum(e0 + e1, red);
  float inv = 1.f / ssum;
  __syncthreads();
  sc[t] = e0 * inv; sc[t + 256] = e1 * inv;
  __syncthreads();
  float acc = 0.f;
  for (int l = 0; l < len; l++) acc += sc[l] * Xb[(size_t)l * DD + t];
  pooled[b * DD + t] = __float2bfloat16(acc);
}

extern "C" void kernel_launch(void* const* d_in, const int* in_sizes, int n_in,
                              void* d_out, int out_size, void* d_ws, size_t ws_size,
                              hipStream_t stream) {
  const int*   tokens  = (const int*)d_in[0];
  const float* tok_emb = (const float*)d_in[2];
  const float* pos_emb = (const float*)d_in[3];
  const float* emb_g   = (const float*)d_in[4];
  const float* emb_b   = (const float*)d_in[5];
  const float* ln1_g   = (const float*)d_in[6];
  const float* ln1_b   = (const float*)d_in[7];
  const float* Wqkv    = (const float*)d_in[8];
  const float* bqkv    = (const float*)d_in[9];
  const float* Wo      = (const float*)d_in[10];
  const float* bo      = (const float*)d_in[11];
  const float* ln2_g   = (const float*)d_in[12];
  const float* ln2_b   = (const float*)d_in[13];
  const float* W1      = (const float*)d_in[14];
  const float* b1      = (const float*)d_in[15];
  const float* W2      = (const float*)d_in[16];
  const float* b2      = (const float*)d_in[17];
  const float* cls_W   = (const float*)d_in[22];
  const float* cls_b   = (const float*)d_in[23];

  // workspace layout (~100.7 MB)
  char* ws = (char*)d_ws;
  float* X     = (float*)ws;                           // 32768*256 f32 = 33,554,432 B
  bf16*  QKV   = (bf16*)(ws + 33554432);               // 32768*768 bf16 = 50,331,648 B (reused as FF1)
  bf16*  Hb    = (bf16*)(ws + 83886080);               // 32768*256 bf16 = 16,777,216 B
  bf16*  POOL  = (bf16*)(ws + 100663296);              // 64*256 bf16
  int*   LEN   = (int*)(ws + 100696064);               // 64 ints

  k_lens<<<BB, 256, 0, stream>>>(tokens, LEN);
  k_embed<<<MM, 256, 0, stream>>>(tokens, tok_emb, pos_emb, emb_g, emb_b, X);

  for (int e = 0; e < KK; e++) {
    k_ln<<<MM, 256, 0, stream>>>(X, ln1_g + e * DD, ln1_b + e * DD, LEN, Hb);
    k_gemm<false, false, true><<<dim3(12, 512), 256, 0, stream>>>(
        Hb, Wqkv + (size_t)e * 3 * DD * DD, bqkv + e * 3 * DD, nullptr, QKV, LEN, 3 * DD, DD);
    k_attn<<<dim3(2, HH, BB), 256, 0, stream>>>(QKV, LEN, Hb);
    k_gemm<false, true, false><<<dim3(4, 512), 256, 0, stream>>>(
        Hb, Wo + (size_t)e * DD * DD, bo + e * DD, X, X, LEN, DD, DD);
    k_ln<<<MM, 256, 0, stream>>>(X, ln2_g + e * DD, ln2_b + e * DD, LEN, Hb);
    k_gemm<true, false, true><<<dim3(8, 512), 256, 0, stream>>>(
        Hb, W1 + (size_t)e * FF * DD, b1 + e * FF, nullptr, QKV, LEN, FF, DD);
    k_gemm<false, true, false><<<dim3(4, 512), 256, 0, stream>>>(
        QKV, W2 + (size_t)e * DD * FF, b2 + e * DD, X, X, LEN, DD, FF);
  }

  k_pool<<<BB, 256, 0, stream>>>(X, LEN, POOL);
  // classifier: logits[64,32000] = pooled @ cls_W^T + cls_b  (reuses GEMM, M=64 -> one m-tile)
  k_gemm<false, false, false><<<dim3(VV / 64, 1), 256, 0, stream>>>(
      POOL, cls_W, cls_b, nullptr, (float*)d_out, LEN, VV, DD);
}

// Round 2
// 1870.499 us; speedup vs baseline: 2.2778x; 2.2778x over previous
//
#include <hip/hip_runtime.h>
#include <hip/hip_bf16.h>

#define BB 64
#define LL 512
#define DD 256
#define VV 32000
#define KK 6
#define HH 4
#define FF 512
#define MM (BB * LL)

typedef __hip_bfloat16 bf16;
typedef unsigned short ushort_t;
typedef __attribute__((ext_vector_type(8))) __bf16 bf16x8;
typedef __attribute__((ext_vector_type(4))) float f32x4;
#define MFMA __builtin_amdgcn_mfma_f32_16x16x32_bf16

__device__ __forceinline__ ushort_t f2bfbits(float x) {
  return __builtin_bit_cast(unsigned short, (__bf16)x);
}

// -------- block reduction --------
__device__ __forceinline__ float blk_sum(float v, float* red) {
  #pragma unroll
  for (int o = 32; o > 0; o >>= 1) v += __shfl_down(v, o, 64);
  __syncthreads();
  if ((threadIdx.x & 63) == 0) red[threadIdx.x >> 6] = v;
  __syncthreads();
  return red[0] + red[1] + red[2] + red[3];
}

__global__ __launch_bounds__(256) void k_lens(const int* __restrict__ tokens, int* __restrict__ lens) {
  __shared__ float red[4];
  int b = blockIdx.x, t = threadIdx.x;
  float c = (tokens[b * LL + t] != 0 ? 1.f : 0.f) + (tokens[b * LL + 256 + t] != 0 ? 1.f : 0.f);
  float s = blk_sum(c, red);
  if (t == 0) lens[b] = (int)(s + 0.5f);
}

__global__ __launch_bounds__(256) void k_embed(const int* __restrict__ tokens,
                                               const float* __restrict__ tok_emb,
                                               const float* __restrict__ pos_emb,
                                               const float* __restrict__ g,
                                               const float* __restrict__ be,
                                               float* __restrict__ X) {
  __shared__ float red[4];
  int row = blockIdx.x;
  int l = row & (LL - 1);
  int t = threadIdx.x;
  int tok = tokens[row];
  float v = tok_emb[(size_t)tok * DD + t] + pos_emb[l * DD + t];
  float mu = blk_sum(v, red) * (1.f / DD);
  float c = v - mu;
  float var = blk_sum(c * c, red) * (1.f / DD);
  X[(size_t)row * DD + t] = c * rsqrtf(var + 1e-5f) * g[t] + be[t];
}

__global__ __launch_bounds__(256) void k_ln(const float* __restrict__ X,
                                            const float* __restrict__ g,
                                            const float* __restrict__ be,
                                            const int* __restrict__ lens,
                                            bf16* __restrict__ H) {
  int row = blockIdx.x;
  int l = row & (LL - 1);
  int b = row >> 9;
  if (l >= lens[b]) return;
  __shared__ float red[4];
  int t = threadIdx.x;
  float v = X[(size_t)row * DD + t];
  float mu = blk_sum(v, red) * (1.f / DD);
  float c = v - mu;
  float var = blk_sum(c * c, red) * (1.f / DD);
  H[(size_t)row * DD + t] = __float2bfloat16(c * rsqrtf(var + 1e-5f) * g[t] + be[t]);
}

// -------- f32 -> bf16 weight conversion --------
__global__ __launch_bounds__(256) void k_cvt(const float* __restrict__ s, ushort_t* __restrict__ d, int n) {
  int i = (blockIdx.x * 256 + threadIdx.x) * 4;
  if (i >= n) return;
  float4 v = *reinterpret_cast<const float4*>(s + i);
  ushort_t o0 = f2bfbits(v.x), o1 = f2bfbits(v.y), o2 = f2bfbits(v.z), o3 = f2bfbits(v.w);
  ushort_t* p = d + i;
  p[0] = o0; p[1] = o1; p[2] = o2; p[3] = o3;
}

// -------- MFMA GEMM: out[M,N] = op(A[M,K]bf16 * W[N,K]bf16^T + bias (+res)) --------
// 128x128 block, 4 waves (2x2), each wave 64x64 = 4x4 fragments, direct-global frags.
template <bool GELU, bool RES, bool OUTBF16>
__global__ __launch_bounds__(256) void k_mgemm(const ushort_t* __restrict__ A,
                                               const ushort_t* __restrict__ Wb,
                                               const float* __restrict__ bias,
                                               const float* __restrict__ res,
                                               void* __restrict__ outp,
                                               const int* __restrict__ lens,
                                               int M, int Ndim, int Kdim) {
  int n0 = blockIdx.x * 128, m0 = blockIdx.y * 128;
  if (M > 128) {
    int b = m0 >> 9, l0 = m0 & (LL - 1);
    if (l0 >= lens[b]) return;
  }
  int t = threadIdx.x, lane = t & 63, wid = t >> 6;
  int wr = (wid >> 1) * 64, wc = (wid & 1) * 64;
  int fr = lane & 15, fg = lane >> 4;

  const ushort_t* Ap[4];
  const ushort_t* Bp[4];
  #pragma unroll
  for (int i = 0; i < 4; i++) {
    int r = m0 + wr + i * 16 + fr;
    if (r > M - 1) r = M - 1;
    Ap[i] = A + (size_t)r * Kdim + fg * 8;
    Bp[i] = Wb + (size_t)(n0 + wc + i * 16 + fr) * Kdim + fg * 8;
  }
  f32x4 acc[4][4];
  #pragma unroll
  for (int i = 0; i < 4; i++)
    #pragma unroll
    for (int j = 0; j < 4; j++) acc[i][j] = (f32x4){0.f, 0.f, 0.f, 0.f};

  for (int k0 = 0; k0 < Kdim; k0 += 32) {
    bf16x8 af[4], bf[4];
    #pragma unroll
    for (int i = 0; i < 4; i++) af[i] = *reinterpret_cast<const bf16x8*>(Ap[i] + k0);
    #pragma unroll
    for (int j = 0; j < 4; j++) bf[j] = *reinterpret_cast<const bf16x8*>(Bp[j] + k0);
    #pragma unroll
    for (int i = 0; i < 4; i++)
      #pragma unroll
      for (int j = 0; j < 4; j++)
        acc[i][j] = MFMA(af[i], bf[j], acc[i][j], 0, 0, 0);
  }

  #pragma unroll
  for (int i = 0; i < 4; i++) {
    int mbase = m0 + wr + i * 16 + fg * 4;
    #pragma unroll
    for (int j = 0; j < 4; j++) {
      int n = n0 + wc + j * 16 + fr;
      float bs = bias[n];
      #pragma unroll
      for (int r = 0; r < 4; r++) {
        int m = mbase + r;
        if (m >= M) continue;
        float v = acc[i][j][r] + bs;
        if (RES) v += res[(size_t)m * Ndim + n];
        if (GELU) v = 0.5f * v * (1.f + erff(v * 0.70710678118f));
        if (OUTBF16) ((bf16*)outp)[(size_t)m * Ndim + n] = __float2bfloat16(v);
        else         ((float*)outp)[(size_t)m * Ndim + n] = v;
      }
    }
  }
}

// -------- MFMA flash attention --------
// grid (L/64, H, B); 4 waves, each owns a 16-query strip; k-tiles of 64.
__global__ __launch_bounds__(256) void k_mattn(const bf16* __restrict__ QKV,
                                               const int* __restrict__ lens,
                                               bf16* __restrict__ O) {
  int b = blockIdx.z, h = blockIdx.y;
  int len = lens[b];
  int q0 = blockIdx.x * 64;
  if (q0 >= len) return;
  int t = threadIdx.x, lane = t & 63, wsid = t >> 6;
  int fr = lane & 15, fg = lane >> 4;
  __shared__ ushort_t VTl[4096];       // V^T 64d x 64k, XOR-swizzled
  __shared__ ushort_t Pl[4][1024];     // per-wave P 16q x 64k, XOR-swizzled

  const ushort_t* base = (const ushort_t*)QKV + (size_t)b * LL * 768;
  const ushort_t* qp = base + (size_t)(q0 + wsid * 16 + fr) * 768 + h * 64 + fg * 8;
  bf16x8 qf0 = *reinterpret_cast<const bf16x8*>(qp);
  bf16x8 qf1 = *reinterpret_cast<const bf16x8*>(qp + 32);

  f32x4 acc_o[4];
  float m_run[4], lpart[4];
  #pragma unroll
  for (int r = 0; r < 4; r++) {
    acc_o[r] = (f32x4){0.f, 0.f, 0.f, 0.f};
    m_run[r] = -1e30f; lpart[r] = 0.f;
  }

  for (int kt = 0; kt < len; kt += 64) {
    __syncthreads();
    // stage V^T (zero rows >= len so no NaN can cross rows via PV)
    {
      int k = t & 63, dg = t >> 6;
      uint4 v0 = {0, 0, 0, 0}, v1 = {0, 0, 0, 0};
      if (kt + k < len) {
        const ushort_t* vp = base + (size_t)(kt + k) * 768 + 512 + h * 64 + dg * 16;
        v0 = *reinterpret_cast<const uint4*>(vp);
        v1 = *reinterpret_cast<const uint4*>(vp + 8);
      }
      unsigned uu[8] = {v0.x, v0.y, v0.z, v0.w, v1.x, v1.y, v1.z, v1.w};
      #pragma unroll
      for (int j = 0; j < 8; j++) {
        int d0 = dg * 16 + j * 2, d1 = d0 + 1;
        VTl[d0 * 64 + (k ^ ((d0 & 7) << 3))] = (ushort_t)(uu[j] & 0xffff);
        VTl[d1 * 64 + (k ^ ((d1 & 7) << 3))] = (ushort_t)(uu[j] >> 16);
      }
    }
    __syncthreads();

    // S = Q K^T  (16q x 64k per wave)
    f32x4 s[4];
    #pragma unroll
    for (int kf = 0; kf < 4; kf++) s[kf] = (f32x4){0.f, 0.f, 0.f, 0.f};
    #pragma unroll
    for (int kf = 0; kf < 4; kf++) {
      const ushort_t* kp = base + (size_t)(kt + kf * 16 + fr) * 768 + 256 + h * 64 + fg * 8;
      bf16x8 kb0 = *reinterpret_cast<const bf16x8*>(kp);
      bf16x8 kb1 = *reinterpret_cast<const bf16x8*>(kp + 32);
      s[kf] = MFMA(qf0, kb0, s[kf], 0, 0, 0);
      s[kf] = MFMA(qf1, kb1, s[kf], 0, 0, 0);
    }
    // scale + key mask (kills any garbage/NaN in masked columns)
    #pragma unroll
    for (int kf = 0; kf < 4; kf++) {
      bool valid = (kt + kf * 16 + fr) < len;
      #pragma unroll
      for (int r = 0; r < 4; r++) s[kf][r] = valid ? s[kf][r] * 0.125f : -1e30f;
    }
    // online softmax per row (row = fg*4+r, cols across 16 lanes x 4 kf)
    #pragma unroll
    for (int r = 0; r < 4; r++) {
      float tm = fmaxf(fmaxf(s[0][r], s[1][r]), fmaxf(s[2][r], s[3][r]));
      tm = fmaxf(tm, __shfl_xor(tm, 1, 64));
      tm = fmaxf(tm, __shfl_xor(tm, 2, 64));
      tm = fmaxf(tm, __shfl_xor(tm, 4, 64));
      tm = fmaxf(tm, __shfl_xor(tm, 8, 64));
      float nm = fmaxf(m_run[r], tm);
      float corr = __expf(m_run[r] - nm);
      m_run[r] = nm;
      float ps = 0.f;
      #pragma unroll
      for (int kf = 0; kf < 4; kf++) {
        float p = __expf(s[kf][r] - nm);
        s[kf][r] = p; ps += p;
      }
      lpart[r] = lpart[r] * corr + ps;
      acc_o[0][r] *= corr; acc_o[1][r] *= corr; acc_o[2][r] *= corr; acc_o[3][r] *= corr;
    }
    // write P (wave-private, swizzled); same-wave DS ops are in-order
    #pragma unroll
    for (int r = 0; r < 4; r++) {
      int q = fg * 4 + r, sw = (q & 7) << 3;
      #pragma unroll
      for (int kf = 0; kf < 4; kf++)
        Pl[wsid][q * 64 + ((kf * 16 + fr) ^ sw)] = f2bfbits(s[kf][r]);
    }
    // O += P @ V
    #pragma unroll
    for (int ss = 0; ss < 2; ss++) {
      bf16x8 pa = *reinterpret_cast<const bf16x8*>(&Pl[wsid][fr * 64 + ((ss * 32 + fg * 8) ^ ((fr & 7) << 3))]);
      #pragma unroll
      for (int df = 0; df < 4; df++) {
        int d = df * 16 + fr;
        bf16x8 vb = *reinterpret_cast<const bf16x8*>(&VTl[d * 64 + ((ss * 32 + fg * 8) ^ ((d & 7) << 3))]);
        acc_o[df] = MFMA(pa, vb, acc_o[df], 0, 0, 0);
      }
    }
  }

  float linv[4];
  #pragma unroll
  for (int r = 0; r < 4; r++) {
    float v = lpart[r];
    v += __shfl_xor(v, 1, 64); v += __shfl_xor(v, 2, 64);
    v += __shfl_xor(v, 4, 64); v += __shfl_xor(v, 8, 64);
    linv[r] = 1.f / v;
  }
  int qrow = b * LL + q0 + wsid * 16 + fg * 4;
  #pragma unroll
  for (int df = 0; df < 4; df++) {
    int d = h * 64 + df * 16 + fr;
    #pragma unroll
    for (int r = 0; r < 4; r++)
      O[(size_t)(qrow + r) * DD + d] = __float2bfloat16(acc_o[df][r] * linv[r]);
  }
}

// -------- final attention pooling --------
__global__ __launch_bounds__(256) void k_pool(const float* __restrict__ X,
                                              const int* __restrict__ lens,
                                              bf16* __restrict__ pooled) {
  __shared__ float red[4];
  __shared__ float qs[DD];
  __shared__ float sc[LL];
  int b = blockIdx.x, t = threadIdx.x;
  int len = lens[b];
  const float* Xb = X + (size_t)b * LL * DD;
  qs[t] = Xb[(size_t)(len - 1) * DD + t];
  __syncthreads();
  for (int l = t; l < LL; l += 256) {
    float s = -1e30f;
    if (l < len) {
      const float4* xr = reinterpret_cast<const float4*>(Xb + (size_t)l * DD);
      const float4* qq = reinterpret_cast<const float4*>(qs);
      float a0 = 0, a1 = 0, a2 = 0, a3 = 0;
      for (int k4 = 0; k4 < 64; k4++) {
        float4 xv = xr[k4], qv = qq[k4];
        a0 += xv.x * qv.x; a1 += xv.y * qv.y; a2 += xv.z * qv.z; a3 += xv.w * qv.w;
      }
      s = (a0 + a1) + (a2 + a3);
    }
    sc[l] = s;
  }
  __syncthreads();
  float mx = fmaxf(sc[t], sc[t + 256]);
  #pragma unroll
  for (int off = 32; off > 0; off >>= 1) mx = fmaxf(mx, __shfl_down(mx, off, 64));
  __syncthreads();
  if ((t & 63) == 0) red[t >> 6] = mx;
  __syncthreads();
  mx = fmaxf(fmaxf(red[0], red[1]), fmaxf(red[2], red[3]));
  float e0 = (t < len) ? __expf(sc[t] - mx) : 0.f;
  float e1 = (t + 256 < len) ? __expf(sc[t + 256] - mx) : 0.f;
  float ssum = blk_sum(e0 + e1, red);
  float inv = 1.f / ssum;
  __syncthreads();
  sc[t] = e0 * inv; sc[t + 256] = e1 * inv;
  __syncthreads();
  float acc = 0.f;
  for (int l = 0; l < len; l++) acc += sc[l] * Xb[(size_t)l * DD + t];
  pooled[b * DD + t] = __float2bfloat16(acc);
}

extern "C" void kernel_launch(void* const* d_in, const int* in_sizes, int n_in,
                              void* d_out, int out_size, void* d_ws, size_t ws_size,
                              hipStream_t stream) {
  const int*   tokens  = (const int*)d_in[0];
  const float* tok_emb = (const float*)d_in[2];
  const float* pos_emb = (const float*)d_in[3];
  const float* emb_g   = (const float*)d_in[4];
  const float* emb_b   = (const float*)d_in[5];
  const float* ln1_g   = (const float*)d_in[6];
  const float* ln1_b   = (const float*)d_in[7];
  const float* Wqkv    = (const float*)d_in[8];
  const float* bqkv    = (const float*)d_in[9];
  const float* Wo      = (const float*)d_in[10];
  const float* bo      = (const float*)d_in[11];
  const float* ln2_g   = (const float*)d_in[12];
  const float* ln2_b   = (const float*)d_in[13];
  const float* W1      = (const float*)d_in[14];
  const float* b1      = (const float*)d_in[15];
  const float* W2      = (const float*)d_in[16];
  const float* b2      = (const float*)d_in[17];
  const float* cls_W   = (const float*)d_in[22];
  const float* cls_b   = (const float*)d_in[23];

  // workspace layout (~101.7 MB)
  char* ws = (char*)d_ws;
  float*    X    = (float*)ws;                         // 33,554,432 B
  ushort_t* QKV  = (ushort_t*)(ws + 33554432);         // 50,331,648 B (also FF1 buffer, also cls_W bf16)
  ushort_t* Hb   = (ushort_t*)(ws + 83886080);         // 16,777,216 B
  ushort_t* WB   = (ushort_t*)(ws + 100663296);        //  1,048,576 B (per-layer bf16 weights)
  ushort_t* POOL = (ushort_t*)(ws + 101711872);        //     32,768 B
  int*      LEN  = (int*)(ws + 101744640);             //        256 B

  const int OFF_QKV = 0, OFF_WO = 196608, OFF_W1 = 262144, OFF_W2 = 393216;

  k_lens<<<BB, 256, 0, stream>>>(tokens, LEN);
  k_embed<<<MM, 256, 0, stream>>>(tokens, tok_emb, pos_emb, emb_g, emb_b, X);

  for (int e = 0; e < KK; e++) {
    k_cvt<<<192, 256, 0, stream>>>(Wqkv + (size_t)e * 196608, WB + OFF_QKV, 196608);
    k_cvt<<<64, 256, 0, stream>>>(Wo + (size_t)e * 65536, WB + OFF_WO, 65536);
    k_cvt<<<128, 256, 0, stream>>>(W1 + (size_t)e * 131072, WB + OFF_W1, 131072);
    k_cvt<<<128, 256, 0, stream>>>(W2 + (size_t)e * 131072, WB + OFF_W2, 131072);

    k_ln<<<MM, 256, 0, stream>>>(X, ln1_g + e * DD, ln1_b + e * DD, LEN, (bf16*)Hb);
    k_mgemm<false, false, true><<<dim3(6, 256), 256, 0, stream>>>(
        Hb, WB + OFF_QKV, bqkv + e * 3 * DD, nullptr, QKV, LEN, MM, 3 * DD, DD);
    k_mattn<<<dim3(8, HH, BB), 256, 0, stream>>>((const bf16*)QKV, LEN, (bf16*)Hb);
    k_mgemm<false, true, false><<<dim3(2, 256), 256, 0, stream>>>(
        Hb, WB + OFF_WO, bo + e * DD, X, X, LEN, MM, DD, DD);
    k_ln<<<MM, 256, 0, stream>>>(X, ln2_g + e * DD, ln2_b + e * DD, LEN, (bf16*)Hb);
    k_mgemm<true, false, true><<<dim3(4, 256), 256, 0, stream>>>(
        Hb, WB + OFF_W1, b1 + e * FF, nullptr, QKV, LEN, MM, FF, DD);
    k_mgemm<false, true, false><<<dim3(2, 256), 256, 0, stream>>>(
        QKV, WB + OFF_W2, b2 + e * DD, X, X, LEN, MM, DD, FF);
  }

  k_pool<<<BB, 256, 0, stream>>>(X, LEN, (bf16*)POOL);
  // classifier: convert cls_W to bf16 into (now free) QKV region, then GEMM
  k_cvt<<<8000, 256, 0, stream>>>(cls_W, QKV, VV * DD);
  k_mgemm<false, false, false><<<dim3(250, 1), 256, 0, stream>>>(
      POOL, QKV, cls_b, nullptr, (float*)d_out, LEN, BB, VV, DD);
}

// Round 3
// 1442.485 us; speedup vs baseline: 2.9537x; 1.2967x over previous
//
#include <hip/hip_runtime.h>
#include <hip/hip_bf16.h>

#define BB 64
#define LL 512
#define DD 256
#define VV 32000
#define KK 6
#define HH 4
#define FF 512
#define MM (BB * LL)

typedef __hip_bfloat16 bf16;
typedef unsigned short ushort_t;
typedef __attribute__((ext_vector_type(8))) __bf16 bf16x8;
typedef __attribute__((ext_vector_type(4))) float f32x4;
#define MFMA __builtin_amdgcn_mfma_f32_16x16x32_bf16

__device__ __forceinline__ ushort_t f2bfbits(float x) {
  return __builtin_bit_cast(unsigned short, (__bf16)x);
}

// async global->LDS, 16B per lane; dest = wave-uniform base + lane*16
__device__ __forceinline__ void gl_lds16(const ushort_t* g, ushort_t* l) {
  __builtin_amdgcn_global_load_lds(
      (const __attribute__((address_space(1))) unsigned int*)g,
      (__attribute__((address_space(3))) unsigned int*)l, 16, 0, 0);
}

// -------- block reduction (only k_lens uses it) --------
__device__ __forceinline__ float blk_sum(float v, float* red) {
  #pragma unroll
  for (int o = 32; o > 0; o >>= 1) v += __shfl_down(v, o, 64);
  __syncthreads();
  if ((threadIdx.x & 63) == 0) red[threadIdx.x >> 6] = v;
  __syncthreads();
  return red[0] + red[1] + red[2] + red[3];
}

__global__ __launch_bounds__(256) void k_lens(const int* __restrict__ tokens, int* __restrict__ lens) {
  __shared__ float red[4];
  int b = blockIdx.x, t = threadIdx.x;
  float c = (tokens[b * LL + t] != 0 ? 1.f : 0.f) + (tokens[b * LL + 256 + t] != 0 ? 1.f : 0.f);
  float s = blk_sum(c, red);
  if (t == 0) lens[b] = (int)(s + 0.5f);
}

// -------- embedding + LN, wave-per-row --------
__global__ __launch_bounds__(256) void k_embed4(const int* __restrict__ tokens,
                                                const float* __restrict__ tok_emb,
                                                const float* __restrict__ pos_emb,
                                                const float* __restrict__ g,
                                                const float* __restrict__ be,
                                                float* __restrict__ X) {
  int wid = threadIdx.x >> 6, lane = threadIdx.x & 63;
  int row = blockIdx.x * 4 + wid;
  int l = row & (LL - 1);
  int tok = tokens[row];
  float4 a = *reinterpret_cast<const float4*>(tok_emb + (size_t)tok * DD + lane * 4);
  float4 p = *reinterpret_cast<const float4*>(pos_emb + (size_t)l * DD + lane * 4);
  float4 v = {a.x + p.x, a.y + p.y, a.z + p.z, a.w + p.w};
  float s = v.x + v.y + v.z + v.w;
  float q = v.x * v.x + v.y * v.y + v.z * v.z + v.w * v.w;
  #pragma unroll
  for (int o = 32; o > 0; o >>= 1) { s += __shfl_xor(s, o, 64); q += __shfl_xor(q, o, 64); }
  float mu = s * (1.f / DD);
  float rstd = rsqrtf(q * (1.f / DD) - mu * mu + 1e-5f);
  float4 gv = *reinterpret_cast<const float4*>(g + lane * 4);
  float4 bv = *reinterpret_cast<const float4*>(be + lane * 4);
  float4 o4 = {(v.x - mu) * rstd * gv.x + bv.x, (v.y - mu) * rstd * gv.y + bv.y,
               (v.z - mu) * rstd * gv.z + bv.z, (v.w - mu) * rstd * gv.w + bv.w};
  *reinterpret_cast<float4*>(X + (size_t)row * DD + lane * 4) = o4;
}

// -------- LN(X) -> bf16, wave-per-row, len-skip --------
__global__ __launch_bounds__(256) void k_ln4(const float* __restrict__ X,
                                             const float* __restrict__ g,
                                             const float* __restrict__ be,
                                             const int* __restrict__ lens,
                                             bf16* __restrict__ H) {
  int wid = threadIdx.x >> 6, lane = threadIdx.x & 63;
  int row = blockIdx.x * 4 + wid;
  int b = row >> 9, l = row & (LL - 1);
  if (l >= lens[b]) return;     // wave-uniform, no barriers in kernel
  float4 v = *reinterpret_cast<const float4*>(X + (size_t)row * DD + lane * 4);
  float s = v.x + v.y + v.z + v.w;
  float q = v.x * v.x + v.y * v.y + v.z * v.z + v.w * v.w;
  #pragma unroll
  for (int o = 32; o > 0; o >>= 1) { s += __shfl_xor(s, o, 64); q += __shfl_xor(q, o, 64); }
  float mu = s * (1.f / DD);
  float rstd = rsqrtf(q * (1.f / DD) - mu * mu + 1e-5f);
  float4 gv = *reinterpret_cast<const float4*>(g + lane * 4);
  float4 bv = *reinterpret_cast<const float4*>(be + lane * 4);
  ushort4 o4;
  o4.x = f2bfbits((v.x - mu) * rstd * gv.x + bv.x);
  o4.y = f2bfbits((v.y - mu) * rstd * gv.y + bv.y);
  o4.z = f2bfbits((v.z - mu) * rstd * gv.z + bv.z);
  o4.w = f2bfbits((v.w - mu) * rstd * gv.w + bv.w);
  *reinterpret_cast<ushort4*>((ushort_t*)H + (size_t)row * DD + lane * 4) = o4;
}

// -------- generic f32 -> bf16 --------
__global__ __launch_bounds__(256) void k_cvt(const float* __restrict__ s, ushort_t* __restrict__ d, int n) {
  int i = (blockIdx.x * 256 + threadIdx.x) * 4;
  if (i >= n) return;
  float4 v = *reinterpret_cast<const float4*>(s + i);
  ushort4 o;
  o.x = f2bfbits(v.x); o.y = f2bfbits(v.y); o.z = f2bfbits(v.z); o.w = f2bfbits(v.w);
  *reinterpret_cast<ushort4*>(d + i) = o;
}

// -------- per-layer weight cvt (4 tensors fused): [Wqkv|Wo|W1|W2] --------
__global__ __launch_bounds__(256) void k_cvtw(const float* __restrict__ w0, const float* __restrict__ w1,
                                              const float* __restrict__ w2, const float* __restrict__ w3,
                                              ushort_t* __restrict__ d) {
  int i = (blockIdx.x * 256 + threadIdx.x) * 4;
  const float* s; int off;
  if (i < 196608)      { s = w0; off = i; }
  else if (i < 262144) { s = w1; off = i - 196608; }
  else if (i < 393216) { s = w2; off = i - 262144; }
  else                 { s = w3; off = i - 393216; }
  float4 v = *reinterpret_cast<const float4*>(s + off);
  ushort4 o;
  o.x = f2bfbits(v.x); o.y = f2bfbits(v.y); o.z = f2bfbits(v.z); o.w = f2bfbits(v.w);
  *reinterpret_cast<ushort4*>(d + i) = o;
}

// -------- MFMA GEMM, m97 structure --------
// 128x128 tile, BK=32, 4 waves (2x2). LDS layout [kgroup][row][8] (conflict-free
// ds_read_b128), filled by global_load_lds with per-lane swizzled source (m173).
template <bool GELU, bool RES, bool OUTBF16>
__global__ __launch_bounds__(256) void k_mgemm(const ushort_t* __restrict__ A,
                                               const ushort_t* __restrict__ Wb,
                                               const float* __restrict__ bias,
                                               const float* __restrict__ res,
                                               void* __restrict__ outp,
                                               const int* __restrict__ lens,
                                               int M, int Ndim, int Kdim) {
  int n0 = blockIdx.x * 128, m0 = blockIdx.y * 128;
  if (M > 128) {
    int b = m0 >> 9;
    if ((m0 & (LL - 1)) >= lens[b]) return;   // uniform: whole tile is padding
  }
  __shared__ __align__(16) ushort_t As[4096];
  __shared__ __align__(16) ushort_t Bs[4096];
  int t = threadIdx.x, lane = t & 63, wid = t >> 6;
  int wr = (wid >> 1) * 64, wc = (wid & 1) * 64;
  int fr = lane & 15, fg = lane >> 4;

  // staging: wave w owns kgroup w (k-offset w*8); rows lane and 64+lane
  int ar0 = m0 + lane;       if (ar0 > M - 1) ar0 = M - 1;
  int ar1 = m0 + 64 + lane;  if (ar1 > M - 1) ar1 = M - 1;
  const ushort_t* ga0 = A + (size_t)ar0 * Kdim + wid * 8;
  const ushort_t* ga1 = A + (size_t)ar1 * Kdim + wid * 8;
  const ushort_t* gb0 = Wb + (size_t)(n0 + lane) * Kdim + wid * 8;
  const ushort_t* gb1 = Wb + (size_t)(n0 + 64 + lane) * Kdim + wid * 8;
  ushort_t* lA0 = &As[wid * 1024];
  ushort_t* lA1 = &As[wid * 1024 + 512];
  ushort_t* lB0 = &Bs[wid * 1024];
  ushort_t* lB1 = &Bs[wid * 1024 + 512];

  f32x4 acc[4][4];
  #pragma unroll
  for (int i = 0; i < 4; i++)
    #pragma unroll
    for (int j = 0; j < 4; j++) acc[i][j] = (f32x4){0.f, 0.f, 0.f, 0.f};

  for (int k0 = 0; k0 < Kdim; k0 += 32) {
    gl_lds16(ga0 + k0, lA0);
    gl_lds16(ga1 + k0, lA1);
    gl_lds16(gb0 + k0, lB0);
    gl_lds16(gb1 + k0, lB1);
    __syncthreads();            // drains vmcnt before barrier
    bf16x8 af[4], bfr[4];
    #pragma unroll
    for (int i = 0; i < 4; i++)
      af[i] = *reinterpret_cast<const bf16x8*>(&As[(fg * 128 + wr + i * 16 + fr) * 8]);
    #pragma unroll
    for (int j = 0; j < 4; j++)
      bfr[j] = *reinterpret_cast<const bf16x8*>(&Bs[(fg * 128 + wc + j * 16 + fr) * 8]);
    #pragma unroll
    for (int i = 0; i < 4; i++)
      #pragma unroll
      for (int j = 0; j < 4; j++)
        acc[i][j] = MFMA(af[i], bfr[j], acc[i][j], 0, 0, 0);
    __syncthreads();
  }

  #pragma unroll
  for (int i = 0; i < 4; i++) {
    int mbase = m0 + wr + i * 16 + fg * 4;
    #pragma unroll
    for (int j = 0; j < 4; j++) {
      int n = n0 + wc + j * 16 + fr;
      float bs = bias[n];
      #pragma unroll
      for (int r = 0; r < 4; r++) {
        int m = mbase + r;
        if (m >= M) continue;
        float v = acc[i][j][r] + bs;
        if (RES) v += res[(size_t)m * Ndim + n];
        if (GELU) v = 0.5f * v * (1.f + erff(v * 0.70710678118f));
        if (OUTBF16) ((bf16*)outp)[(size_t)m * Ndim + n] = __float2bfloat16(v);
        else         ((float*)outp)[(size_t)m * Ndim + n] = v;
      }
    }
  }
}

// -------- MFMA flash attention (unchanged from round 1) --------
__global__ __launch_bounds__(256) void k_mattn(const bf16* __restrict__ QKV,
                                               const int* __restrict__ lens,
                                               bf16* __restrict__ O) {
  int b = blockIdx.z, h = blockIdx.y;
  int len = lens[b];
  int q0 = blockIdx.x * 64;
  if (q0 >= len) return;
  int t = threadIdx.x, lane = t & 63, wsid = t >> 6;
  int fr = lane & 15, fg = lane >> 4;
  __shared__ ushort_t VTl[4096];
  __shared__ ushort_t Pl[4][1024];

  const ushort_t* base = (const ushort_t*)QKV + (size_t)b * LL * 768;
  const ushort_t* qp = base + (size_t)(q0 + wsid * 16 + fr) * 768 + h * 64 + fg * 8;
  bf16x8 qf0 = *reinterpret_cast<const bf16x8*>(qp);
  bf16x8 qf1 = *reinterpret_cast<const bf16x8*>(qp + 32);

  f32x4 acc_o[4];
  float m_run[4], lpart[4];
  #pragma unroll
  for (int r = 0; r < 4; r++) {
    acc_o[r] = (f32x4){0.f, 0.f, 0.f, 0.f};
    m_run[r] = -1e30f; lpart[r] = 0.f;
  }

  for (int kt = 0; kt < len; kt += 64) {
    __syncthreads();
    {
      int k = t & 63, dg = t >> 6;
      uint4 v0 = {0, 0, 0, 0}, v1 = {0, 0, 0, 0};
      if (kt + k < len) {
        const ushort_t* vp = base + (size_t)(kt + k) * 768 + 512 + h * 64 + dg * 16;
        v0 = *reinterpret_cast<const uint4*>(vp);
        v1 = *reinterpret_cast<const uint4*>(vp + 8);
      }
      unsigned uu[8] = {v0.x, v0.y, v0.z, v0.w, v1.x, v1.y, v1.z, v1.w};
      #pragma unroll
      for (int j = 0; j < 8; j++) {
        int d0 = dg * 16 + j * 2, d1 = d0 + 1;
        VTl[d0 * 64 + (k ^ ((d0 & 7) << 3))] = (ushort_t)(uu[j] & 0xffff);
        VTl[d1 * 64 + (k ^ ((d1 & 7) << 3))] = (ushort_t)(uu[j] >> 16);
      }
    }
    __syncthreads();

    f32x4 s[4];
    #pragma unroll
    for (int kf = 0; kf < 4; kf++) s[kf] = (f32x4){0.f, 0.f, 0.f, 0.f};
    #pragma unroll
    for (int kf = 0; kf < 4; kf++) {
      const ushort_t* kp = base + (size_t)(kt + kf * 16 + fr) * 768 + 256 + h * 64 + fg * 8;
      bf16x8 kb0 = *reinterpret_cast<const bf16x8*>(kp);
      bf16x8 kb1 = *reinterpret_cast<const bf16x8*>(kp + 32);
      s[kf] = MFMA(qf0, kb0, s[kf], 0, 0, 0);
      s[kf] = MFMA(qf1, kb1, s[kf], 0, 0, 0);
    }
    #pragma unroll
    for (int kf = 0; kf < 4; kf++) {
      bool valid = (kt + kf * 16 + fr) < len;
      #pragma unroll
      for (int r = 0; r < 4; r++) s[kf][r] = valid ? s[kf][r] * 0.125f : -1e30f;
    }
    #pragma unroll
    for (int r = 0; r < 4; r++) {
      float tm = fmaxf(fmaxf(s[0][r], s[1][r]), fmaxf(s[2][r], s[3][r]));
      tm = fmaxf(tm, __shfl_xor(tm, 1, 64));
      tm = fmaxf(tm, __shfl_xor(tm, 2, 64));
      tm = fmaxf(tm, __shfl_xor(tm, 4, 64));
      tm = fmaxf(tm, __shfl_xor(tm, 8, 64));
      float nm = fmaxf(m_run[r], tm);
      float corr = __expf(m_run[r] - nm);
      m_run[r] = nm;
      float ps = 0.f;
      #pragma unroll
      for (int kf = 0; kf < 4; kf++) {
        float p = __expf(s[kf][r] - nm);
        s[kf][r] = p; ps += p;
      }
      lpart[r] = lpart[r] * corr + ps;
      acc_o[0][r] *= corr; acc_o[1][r] *= corr; acc_o[2][r] *= corr; acc_o[3][r] *= corr;
    }
    #pragma unroll
    for (int r = 0; r < 4; r++) {
      int q = fg * 4 + r, sw = (q & 7) << 3;
      #pragma unroll
      for (int kf = 0; kf < 4; kf++)
        Pl[wsid][q * 64 + ((kf * 16 + fr) ^ sw)] = f2bfbits(s[kf][r]);
    }
    #pragma unroll
    for (int ss = 0; ss < 2; ss++) {
      bf16x8 pa = *reinterpret_cast<const bf16x8*>(&Pl[wsid][fr * 64 + ((ss * 32 + fg * 8) ^ ((fr & 7) << 3))]);
      #pragma unroll
      for (int df = 0; df < 4; df++) {
        int d = df * 16 + fr;
        bf16x8 vb = *reinterpret_cast<const bf16x8*>(&VTl[d * 64 + ((ss * 32 + fg * 8) ^ ((d & 7) << 3))]);
        acc_o[df] = MFMA(pa, vb, acc_o[df], 0, 0, 0);
      }
    }
  }

  float linv[4];
  #pragma unroll
  for (int r = 0; r < 4; r++) {
    float v = lpart[r];
    v += __shfl_xor(v, 1, 64); v += __shfl_xor(v, 2, 64);
    v += __shfl_xor(v, 4, 64); v += __shfl_xor(v, 8, 64);
    linv[r] = 1.f / v;
  }
  int qrow = b * LL + q0 + wsid * 16 + fg * 4;
  #pragma unroll
  for (int df = 0; df < 4; df++) {
    int d = h * 64 + df * 16 + fr;
    #pragma unroll
    for (int r = 0; r < 4; r++)
      O[(size_t)(qrow + r) * DD + d] = __float2bfloat16(acc_o[df][r] * linv[r]);
  }
}

// -------- final attention pooling --------
__global__ __launch_bounds__(256) void k_pool(const float* __restrict__ X,
                                              const int* __restrict__ lens,
                                              bf16* __restrict__ pooled) {
  __shared__ float red[4];
  __shared__ float qs[DD];
  __shared__ float sc[LL];
  int b = blockIdx.x, t = threadIdx.x;
  int len = lens[b];
  const float* Xb = X + (size_t)b * LL * DD;
  qs[t] = Xb[(size_t)(len - 1) * DD + t];
  __syncthreads();
  for (int l = t; l < LL; l += 256) {
    float s = -1e30f;
    if (l < len) {
      const float4* xr = reinterpret_cast<const float4*>(Xb + (size_t)l * DD);
      const float4* qq = reinterpret_cast<const float4*>(qs);
      float a0 = 0, a1 = 0, a2 = 0, a3 = 0;
      for (int k4 = 0; k4 < 64; k4++) {
        float4 xv = xr[k4], qv = qq[k4];
        a0 += xv.x * qv.x; a1 += xv.y * qv.y; a2 += xv.z * qv.z; a3 += xv.w * qv.w;
      }
      s = (a0 + a1) + (a2 + a3);
    }
    sc[l] = s;
  }
  __syncthreads();
  float mx = fmaxf(sc[t], sc[t + 256]);
  #pragma unroll
  for (int off = 32; off > 0; off >>= 1) mx = fmaxf(mx, __shfl_down(mx, off, 64));
  __syncthreads();
  if ((t & 63) == 0) red[t >> 6] = mx;
  __syncthreads();
  mx = fmaxf(fmaxf(red[0], red[1]), fmaxf(red[2], red[3]));
  float e0 = (t < len) ? __expf(sc[t] - mx) : 0.f;
  float e1 = (t + 256 < len) ? __expf(sc[t + 256] - mx) : 0.f;
  float ssum = blk_sum(e0 + e1, red);
  float inv = 1.f / ssum;
  __syncthreads();
  sc[t] = e0 * inv; sc[t + 256] = e1 * inv;
  __syncthreads();
  float acc = 0.f;
  for (int l = 0; l < len; l++) acc += sc[l] * Xb[(size_t)l * DD + t];
  pooled[b * DD + t] = __float2bfloat16(acc);
}

extern "C" void kernel_launch(void* const* d_in, const int* in_sizes, int n_in,
                              void* d_out, int out_size, void* d_ws, size_t ws_size,
                              hipStream_t stream) {
  const int*   tokens  = (const int*)d_in[0];
  const float* tok_emb = (const float*)d_in[2];
  const float* pos_emb = (const float*)d_in[3];
  const float* emb_g   = (const float*)d_in[4];
  const float* emb_b   = (const float*)d_in[5];
  const float* ln1_g   = (const float*)d_in[6];
  const float* ln1_b   = (const float*)d_in[7];
  const float* Wqkv    = (const float*)d_in[8];
  const float* bqkv    = (const float*)d_in[9];
  const float* Wo      = (const float*)d_in[10];
  const float* bo      = (const float*)d_in[11];
  const float* ln2_g   = (const float*)d_in[12];
  const float* ln2_b   = (const float*)d_in[13];
  const float* W1      = (const float*)d_in[14];
  const float* b1      = (const float*)d_in[15];
  const float* W2      = (const float*)d_in[16];
  const float* b2      = (const float*)d_in[17];
  const float* cls_W   = (const float*)d_in[22];
  const float* cls_b   = (const float*)d_in[23];

  // workspace layout (~101.7 MB, known-good size)
  char* ws = (char*)d_ws;
  float*    X    = (float*)ws;                         // 33,554,432 B
  ushort_t* QKV  = (ushort_t*)(ws + 33554432);         // 50,331,648 B (QKV / FF1 / cls_W bf16)
  ushort_t* Hb   = (ushort_t*)(ws + 83886080);         // 16,777,216 B
  ushort_t* WB   = (ushort_t*)(ws + 100663296);        //  1,048,576 B per-layer weights bf16
  ushort_t* POOL = (ushort_t*)(ws + 101711872);        //     32,768 B
  int*      LEN  = (int*)(ws + 101744640);             //        256 B

  const int OFF_QKV = 0, OFF_WO = 196608, OFF_W1 = 262144, OFF_W2 = 393216;

  k_lens<<<BB, 256, 0, stream>>>(tokens, LEN);
  k_embed4<<<MM / 4, 256, 0, stream>>>(tokens, tok_emb, pos_emb, emb_g, emb_b, X);

  for (int e = 0; e < KK; e++) {
    k_cvtw<<<512, 256, 0, stream>>>(Wqkv + (size_t)e * 196608, Wo + (size_t)e * 65536,
                                    W1 + (size_t)e * 131072, W2 + (size_t)e * 131072, WB);
    k_ln4<<<MM / 4, 256, 0, stream>>>(X, ln1_g + e * DD, ln1_b + e * DD, LEN, (bf16*)Hb);
    k_mgemm<false, false, true><<<dim3(6, 256), 256, 0, stream>>>(
        Hb, WB + OFF_QKV, bqkv + e * 3 * DD, nullptr, QKV, LEN, MM, 3 * DD, DD);
    k_mattn<<<dim3(8, HH, BB), 256, 0, stream>>>((const bf16*)QKV, LEN, (bf16*)Hb);
    k_mgemm<false, true, false><<<dim3(2, 256), 256, 0, stream>>>(
        Hb, WB + OFF_WO, bo + e * DD, X, X, LEN, MM, DD, DD);
    k_ln4<<<MM / 4, 256, 0, stream>>>(X, ln2_g + e * DD, ln2_b + e * DD, LEN, (bf16*)Hb);
    k_mgemm<true, false, true><<<dim3(4, 256), 256, 0, stream>>>(
        Hb, WB + OFF_W1, b1 + e * FF, nullptr, QKV, LEN, MM, FF, DD);
    k_mgemm<false, true, false><<<dim3(2, 256), 256, 0, stream>>>(
        QKV, WB + OFF_W2, b2 + e * DD, X, X, LEN, MM, DD, FF);
  }

  k_pool<<<BB, 256, 0, stream>>>(X, LEN, (bf16*)POOL);
  k_cvt<<<8000, 256, 0, stream>>>(cls_W, QKV, VV * DD);
  k_mgemm<false, false, false><<<dim3(250, 1), 256, 0, stream>>>(
      POOL, QKV, cls_b, nullptr, (float*)d_out, LEN, BB, VV, DD);
}

// Round 4
// 1327.131 us; speedup vs baseline: 3.2104x; 1.0869x over previous
//
#include <hip/hip_runtime.h>
#include <hip/hip_bf16.h>

#define BB 64
#define LL 512
#define DD 256
#define VV 32000
#define KK 6
#define HH 4
#define FF 512
#define MM (BB * LL)

typedef __hip_bfloat16 bf16;
typedef unsigned short ushort_t;
typedef __attribute__((ext_vector_type(8))) __bf16 bf16x8;
typedef __attribute__((ext_vector_type(4))) float f32x4;
#define MFMA __builtin_amdgcn_mfma_f32_16x16x32_bf16

__device__ __forceinline__ ushort_t f2bfbits(float x) {
  return __builtin_bit_cast(unsigned short, (__bf16)x);
}
__device__ __forceinline__ unsigned pkbf(float lo, float hi) {
  return (unsigned)f2bfbits(lo) | ((unsigned)f2bfbits(hi) << 16);
}
union U8 { unsigned u[4]; bf16x8 v; };

// async global->LDS, 16B/lane; dest = wave-uniform base + lane*16
__device__ __forceinline__ void gl_lds16(const ushort_t* g, ushort_t* l) {
  __builtin_amdgcn_global_load_lds(
      (const __attribute__((address_space(1))) unsigned int*)g,
      (__attribute__((address_space(3))) unsigned int*)l, 16, 0, 0);
}

__device__ __forceinline__ float blk_sum(float v, float* red) {
  #pragma unroll
  for (int o = 32; o > 0; o >>= 1) v += __shfl_down(v, o, 64);
  __syncthreads();
  if ((threadIdx.x & 63) == 0) red[threadIdx.x >> 6] = v;
  __syncthreads();
  return red[0] + red[1] + red[2] + red[3];
}

__global__ __launch_bounds__(256) void k_lens(const int* __restrict__ tokens, int* __restrict__ lens) {
  __shared__ float red[4];
  int b = blockIdx.x, t = threadIdx.x;
  float c = (tokens[b * LL + t] != 0 ? 1.f : 0.f) + (tokens[b * LL + 256 + t] != 0 ? 1.f : 0.f);
  float s = blk_sum(c, red);
  if (t == 0) lens[b] = (int)(s + 0.5f);
}

__global__ __launch_bounds__(256) void k_embed4(const int* __restrict__ tokens,
                                                const float* __restrict__ tok_emb,
                                                const float* __restrict__ pos_emb,
                                                const float* __restrict__ g,
                                                const float* __restrict__ be,
                                                float* __restrict__ X) {
  int wid = threadIdx.x >> 6, lane = threadIdx.x & 63;
  int row = blockIdx.x * 4 + wid;
  int l = row & (LL - 1);
  int tok = tokens[row];
  float4 a = *reinterpret_cast<const float4*>(tok_emb + (size_t)tok * DD + lane * 4);
  float4 p = *reinterpret_cast<const float4*>(pos_emb + (size_t)l * DD + lane * 4);
  float4 v = {a.x + p.x, a.y + p.y, a.z + p.z, a.w + p.w};
  float s = v.x + v.y + v.z + v.w;
  float q = v.x * v.x + v.y * v.y + v.z * v.z + v.w * v.w;
  #pragma unroll
  for (int o = 32; o > 0; o >>= 1) { s += __shfl_xor(s, o, 64); q += __shfl_xor(q, o, 64); }
  float mu = s * (1.f / DD);
  float rstd = rsqrtf(q * (1.f / DD) - mu * mu + 1e-5f);
  float4 gv = *reinterpret_cast<const float4*>(g + lane * 4);
  float4 bv = *reinterpret_cast<const float4*>(be + lane * 4);
  float4 o4 = {(v.x - mu) * rstd * gv.x + bv.x, (v.y - mu) * rstd * gv.y + bv.y,
               (v.z - mu) * rstd * gv.z + bv.z, (v.w - mu) * rstd * gv.w + bv.w};
  *reinterpret_cast<float4*>(X + (size_t)row * DD + lane * 4) = o4;
}

__global__ __launch_bounds__(256) void k_ln4(const float* __restrict__ X,
                                             const float* __restrict__ g,
                                             const float* __restrict__ be,
                                             const int* __restrict__ lens,
                                             bf16* __restrict__ H) {
  int wid = threadIdx.x >> 6, lane = threadIdx.x & 63;
  int row = blockIdx.x * 4 + wid;
  int b = row >> 9, l = row & (LL - 1);
  if (l >= lens[b]) return;
  float4 v = *reinterpret_cast<const float4*>(X + (size_t)row * DD + lane * 4);
  float s = v.x + v.y + v.z + v.w;
  float q = v.x * v.x + v.y * v.y + v.z * v.z + v.w * v.w;
  #pragma unroll
  for (int o = 32; o > 0; o >>= 1) { s += __shfl_xor(s, o, 64); q += __shfl_xor(q, o, 64); }
  float mu = s * (1.f / DD);
  float rstd = rsqrtf(q * (1.f / DD) - mu * mu + 1e-5f);
  float4 gv = *reinterpret_cast<const float4*>(g + lane * 4);
  float4 bv = *reinterpret_cast<const float4*>(be + lane * 4);
  ushort4 o4;
  o4.x = f2bfbits((v.x - mu) * rstd * gv.x + bv.x);
  o4.y = f2bfbits((v.y - mu) * rstd * gv.y + bv.y);
  o4.z = f2bfbits((v.z - mu) * rstd * gv.z + bv.z);
  o4.w = f2bfbits((v.w - mu) * rstd * gv.w + bv.w);
  *reinterpret_cast<ushort4*>((ushort_t*)H + (size_t)row * DD + lane * 4) = o4;
}

__global__ __launch_bounds__(256) void k_cvtw(const float* __restrict__ w0, const float* __restrict__ w1,
                                              const float* __restrict__ w2, const float* __restrict__ w3,
                                              ushort_t* __restrict__ d) {
  int i = (blockIdx.x * 256 + threadIdx.x) * 4;
  const float* s; int off;
  if (i < 196608)      { s = w0; off = i; }
  else if (i < 262144) { s = w1; off = i - 196608; }
  else if (i < 393216) { s = w2; off = i - 262144; }
  else                 { s = w3; off = i - 393216; }
  float4 v = *reinterpret_cast<const float4*>(s + off);
  ushort4 o;
  o.x = f2bfbits(v.x); o.y = f2bfbits(v.y); o.z = f2bfbits(v.z); o.w = f2bfbits(v.w);
  *reinterpret_cast<ushort4*>(d + i) = o;
}

// -------- MFMA GEMM, double-buffered 2-phase (T3 minimum) --------
template <bool GELU, bool RES, bool OUTBF16>
__global__ __launch_bounds__(256) void k_mgemm(const ushort_t* __restrict__ A,
                                               const ushort_t* __restrict__ Wb,
                                               const float* __restrict__ bias,
                                               const float* __restrict__ res,
                                               void* __restrict__ outp,
                                               const int* __restrict__ lens,
                                               int M, int Ndim, int Kdim) {
  int n0 = blockIdx.x * 128, m0 = blockIdx.y * 128;
  if (M > 128) {
    int b = m0 >> 9;
    if ((m0 & (LL - 1)) >= lens[b]) return;
  }
  __shared__ __align__(16) ushort_t As[2][4096];
  __shared__ __align__(16) ushort_t Bs[2][4096];
  int t = threadIdx.x, lane = t & 63, wid = t >> 6;
  int wr = (wid >> 1) * 64, wc = (wid & 1) * 64;
  int fr = lane & 15, fg = lane >> 4;

  int ar0 = m0 + lane;       if (ar0 > M - 1) ar0 = M - 1;
  int ar1 = m0 + 64 + lane;  if (ar1 > M - 1) ar1 = M - 1;
  const ushort_t* ga0 = A + (size_t)ar0 * Kdim + wid * 8;
  const ushort_t* ga1 = A + (size_t)ar1 * Kdim + wid * 8;
  const ushort_t* gb0 = Wb + (size_t)(n0 + lane) * Kdim + wid * 8;
  const ushort_t* gb1 = Wb + (size_t)(n0 + 64 + lane) * Kdim + wid * 8;

  f32x4 acc[4][4];
  #pragma unroll
  for (int i = 0; i < 4; i++)
    #pragma unroll
    for (int j = 0; j < 4; j++) acc[i][j] = (f32x4){0.f, 0.f, 0.f, 0.f};

  int nk = Kdim >> 5;
  // prologue
  gl_lds16(ga0, &As[0][wid * 1024]);
  gl_lds16(ga1, &As[0][wid * 1024 + 512]);
  gl_lds16(gb0, &Bs[0][wid * 1024]);
  gl_lds16(gb1, &Bs[0][wid * 1024 + 512]);
  __syncthreads();
  for (int kt = 0; kt < nk; kt++) {
    int cur = kt & 1;
    if (kt + 1 < nk) {
      int ko = (kt + 1) << 5;
      int nxt = cur ^ 1;
      gl_lds16(ga0 + ko, &As[nxt][wid * 1024]);
      gl_lds16(ga1 + ko, &As[nxt][wid * 1024 + 512]);
      gl_lds16(gb0 + ko, &Bs[nxt][wid * 1024]);
      gl_lds16(gb1 + ko, &Bs[nxt][wid * 1024 + 512]);
    }
    bf16x8 af[4], bfr[4];
    #pragma unroll
    for (int i = 0; i < 4; i++)
      af[i] = *reinterpret_cast<const bf16x8*>(&As[cur][(fg * 128 + wr + i * 16 + fr) * 8]);
    #pragma unroll
    for (int j = 0; j < 4; j++)
      bfr[j] = *reinterpret_cast<const bf16x8*>(&Bs[cur][(fg * 128 + wc + j * 16 + fr) * 8]);
    #pragma unroll
    for (int i = 0; i < 4; i++)
      #pragma unroll
      for (int j = 0; j < 4; j++)
        acc[i][j] = MFMA(af[i], bfr[j], acc[i][j], 0, 0, 0);
    __syncthreads();
  }

  #pragma unroll
  for (int i = 0; i < 4; i++) {
    int mbase = m0 + wr + i * 16 + fg * 4;
    #pragma unroll
    for (int j = 0; j < 4; j++) {
      int n = n0 + wc + j * 16 + fr;
      float bs = bias[n];
      #pragma unroll
      for (int r = 0; r < 4; r++) {
        int m = mbase + r;
        if (m >= M) continue;
        float v = acc[i][j][r] + bs;
        if (RES) v += res[(size_t)m * Ndim + n];
        if (GELU) v = 0.5f * v * (1.f + erff(v * 0.70710678118f));
        if (OUTBF16) ((bf16*)outp)[(size_t)m * Ndim + n] = __float2bfloat16(v);
        else         ((float*)outp)[(size_t)m * Ndim + n] = v;
      }
    }
  }
}

// -------- MFMA flash attention v2 --------
// grid (4 qchunks of 128, H, B); 512 thr / 8 waves, 16 q per wave.
// K [512][64] staged once via global_load_lds (pre-swizzled source),
// V^T [64][512] staged once (scalar transpose, swizzled chunks).
// Swapped-operand S: q lives on fr -> scalar softmax state per lane,
// P reaches PV B-frag via shfl (no LDS round trip). PV computes O^T.
__global__ __launch_bounds__(512) void k_mattn2(const ushort_t* __restrict__ QKV,
                                                const int* __restrict__ lens,
                                                ushort_t* __restrict__ O) {
  int b = blockIdx.z, h = blockIdx.y;
  int len = lens[b];
  int q0 = blockIdx.x * 128;
  if (q0 >= len) return;
  int t = threadIdx.x, lane = t & 63, w = t >> 6;
  int fr = lane & 15, fg = lane >> 4;
  __shared__ __align__(16) ushort_t Kl[32768];   // [k 512][d 64], chunk^=(k&7)
  __shared__ __align__(16) ushort_t Vt[32768];   // [d 64][k 512], chunk^=(d&7)
  const ushort_t* base = QKV + (size_t)b * LL * 768;
  int klim = (len + 63) & ~63;
  int nrounds = klim >> 6;

  // stage K: linear dest, inverse-swizzled per-lane source
  for (int rd = 0; rd < 8; rd++) {
    if (rd >= nrounds) break;              // uniform
    int row = rd * 64 + (t >> 3);
    int chunk = t & 7;
    int rowc = row < len ? row : len - 1;
    const ushort_t* src = base + (size_t)rowc * 768 + 256 + h * 64 + ((chunk ^ (row & 7)) * 8);
    gl_lds16(src, &Kl[rd * 4096 + w * 512]);
  }
  // stage V^T: coalesced reads, scalar swizzled stores; zero-fill k in [len, klim)
  for (int it = 0; it < 8; it++) {
    int c = it * 512 + t;
    int k = c >> 3, dg = c & 7;
    if (k >= klim) continue;
    uint4 vv = {0, 0, 0, 0};
    if (k < len) vv = *reinterpret_cast<const uint4*>(base + (size_t)k * 768 + 512 + h * 64 + dg * 8);
    unsigned uu[4] = {vv.x, vv.y, vv.z, vv.w};
    #pragma unroll
    for (int j = 0; j < 4; j++) {
      int d0 = dg * 8 + j * 2, d1 = d0 + 1;
      Vt[d0 * 512 + (((k >> 3) ^ (d0 & 7)) * 8) + (k & 7)] = (ushort_t)(uu[j] & 0xffff);
      Vt[d1 * 512 + (((k >> 3) ^ (d1 & 7)) * 8) + (k & 7)] = (ushort_t)(uu[j] >> 16);
    }
  }
  __syncthreads();

  int qw = q0 + w * 16;
  if (qw >= len) return;                   // wave-uniform, after the only barrier
  int q = qw + fr;

  const ushort_t* qp = base + (size_t)q * 768 + h * 64 + fg * 8;
  bf16x8 qf0 = *reinterpret_cast<const bf16x8*>(qp);
  bf16x8 qf1 = *reinterpret_cast<const bf16x8*>(qp + 32);

  f32x4 ot[4];
  #pragma unroll
  for (int df = 0; df < 4; df++) ot[df] = (f32x4){0.f, 0.f, 0.f, 0.f};
  float m_run = -1e30f, lsum = 0.f;

  for (int kt = 0; kt < len; kt += 64) {
    // S^T = K·Q^T : k on (fg,r), q on fr
    f32x4 s[4];
    #pragma unroll
    for (int f = 0; f < 4; f++) {
      s[f] = (f32x4){0.f, 0.f, 0.f, 0.f};
      int krow = kt + f * 16 + fr;
      const ushort_t* kp0 = &Kl[krow * 64 + ((fg ^ (krow & 7)) * 8)];
      const ushort_t* kp1 = &Kl[krow * 64 + (((4 + fg) ^ (krow & 7)) * 8)];
      s[f] = MFMA(*reinterpret_cast<const bf16x8*>(kp0), qf0, s[f], 0, 0, 0);
      s[f] = MFMA(*reinterpret_cast<const bf16x8*>(kp1), qf1, s[f], 0, 0, 0);
    }
    int rem = len - kt;
    #pragma unroll
    for (int f = 0; f < 4; f++)
      #pragma unroll
      for (int r = 0; r < 4; r++)
        s[f][r] = (f * 16 + fg * 4 + r < rem) ? s[f][r] * 0.125f : -1e30f;
    // row reduce across fg groups (lanes sharing fr)
    float tm = -1e30f;
    #pragma unroll
    for (int f = 0; f < 4; f++)
      #pragma unroll
      for (int r = 0; r < 4; r++) tm = fmaxf(tm, s[f][r]);
    tm = fmaxf(tm, __shfl_xor(tm, 16, 64));
    tm = fmaxf(tm, __shfl_xor(tm, 32, 64));
    float m_new = fmaxf(m_run, tm);
    float corr = __expf(m_run - m_new);
    float ps = 0.f;
    #pragma unroll
    for (int f = 0; f < 4; f++)
      #pragma unroll
      for (int r = 0; r < 4; r++) {
        float p = __expf(s[f][r] - m_new);
        s[f][r] = p; ps += p;
      }
    ps += __shfl_xor(ps, 16, 64);
    ps += __shfl_xor(ps, 32, 64);
    lsum = lsum * corr + ps;
    m_run = m_new;
    #pragma unroll
    for (int df = 0; df < 4; df++)
      #pragma unroll
      for (int r = 0; r < 4; r++) ot[df][r] *= corr;
    // PV: O^T += Vt · P^T, P B-frag built via shfl
    #pragma unroll
    for (int st = 0; st < 2; st++) {
      int fA = st * 2, fB = fA + 1;
      unsigned a0 = pkbf(s[fA][0], s[fA][1]), a1 = pkbf(s[fA][2], s[fA][3]);
      unsigned b0 = pkbf(s[fB][0], s[fB][1]), b1 = pkbf(s[fB][2], s[fB][3]);
      int sA = ((fg & 1) * 2) * 16 + fr;
      int sB = sA + 16;
      unsigned wa0 = __shfl(a0, sA, 64), wb0 = __shfl(b0, sA, 64);
      unsigned wa1 = __shfl(a1, sA, 64), wb1 = __shfl(b1, sA, 64);
      unsigned wa2 = __shfl(a0, sB, 64), wb2 = __shfl(b0, sB, 64);
      unsigned wa3 = __shfl(a1, sB, 64), wb3 = __shfl(b1, sB, 64);
      bool lo = fg < 2;
      U8 pf;
      pf.u[0] = lo ? wa0 : wb0; pf.u[1] = lo ? wa1 : wb1;
      pf.u[2] = lo ? wa2 : wb2; pf.u[3] = lo ? wa3 : wb3;
      int cb = (kt >> 3) + st * 4 + fg;
      #pragma unroll
      for (int df = 0; df < 4; df++) {
        int d = df * 16 + fr;
        const ushort_t* vp = &Vt[d * 512 + ((cb ^ (d & 7)) * 8)];
        ot[df] = MFMA(*reinterpret_cast<const bf16x8*>(vp), pf.v, ot[df], 0, 0, 0);
      }
    }
  }

  float linv = 1.f / lsum;
  if (q < len) {
    #pragma unroll
    for (int df = 0; df < 4; df++) {
      ushort4 ov;
      ov.x = f2bfbits(ot[df][0] * linv);
      ov.y = f2bfbits(ot[df][1] * linv);
      ov.z = f2bfbits(ot[df][2] * linv);
      ov.w = f2bfbits(ot[df][3] * linv);
      *reinterpret_cast<ushort4*>(O + (size_t)(b * LL + q) * DD + h * 64 + df * 16 + fg * 4) = ov;
    }
  }
}

// -------- final attention pooling --------
__global__ __launch_bounds__(256) void k_pool(const float* __restrict__ X,
                                              const int* __restrict__ lens,
                                              bf16* __restrict__ pooled) {
  __shared__ float red[4];
  __shared__ float qs[DD];
  __shared__ float sc[LL];
  int b = blockIdx.x, t = threadIdx.x;
  int len = lens[b];
  const float* Xb = X + (size_t)b * LL * DD;
  qs[t] = Xb[(size_t)(len - 1) * DD + t];
  __syncthreads();
  for (int l = t; l < LL; l += 256) {
    float s = -1e30f;
    if (l < len) {
      const float4* xr = reinterpret_cast<const float4*>(Xb + (size_t)l * DD);
      const float4* qq = reinterpret_cast<const float4*>(qs);
      float a0 = 0, a1 = 0, a2 = 0, a3 = 0;
      for (int k4 = 0; k4 < 64; k4++) {
        float4 xv = xr[k4], qv = qq[k4];
        a0 += xv.x * qv.x; a1 += xv.y * qv.y; a2 += xv.z * qv.z; a3 += xv.w * qv.w;
      }
      s = (a0 + a1) + (a2 + a3);
    }
    sc[l] = s;
  }
  __syncthreads();
  float mx = fmaxf(sc[t], sc[t + 256]);
  #pragma unroll
  for (int off = 32; off > 0; off >>= 1) mx = fmaxf(mx, __shfl_down(mx, off, 64));
  __syncthreads();
  if ((t & 63) == 0) red[t >> 6] = mx;
  __syncthreads();
  mx = fmaxf(fmaxf(red[0], red[1]), fmaxf(red[2], red[3]));
  float e0 = (t < len) ? __expf(sc[t] - mx) : 0.f;
  float e1 = (t + 256 < len) ? __expf(sc[t + 256] - mx) : 0.f;
  float ssum = blk_sum(e0 + e1, red);
  float inv = 1.f / ssum;
  __syncthreads();
  sc[t] = e0 * inv; sc[t + 256] = e1 * inv;
  __syncthreads();
  float acc = 0.f;
  for (int l = 0; l < len; l++) acc += sc[l] * Xb[(size_t)l * DD + t];
  pooled[b * DD + t] = __float2bfloat16(acc);
}

// -------- classifier: logits[64,32000] = POOL(bf16) @ cls_W(f32->bf16 in reg)^T + b --------
// grid 250, 512 thr / 8 waves, 16 n per wave; M=64 = 4 m-frags exactly.
__global__ __launch_bounds__(512) void k_cls(const ushort_t* __restrict__ POOL,
                                             const float* __restrict__ W,
                                             const float* __restrict__ bias,
                                             float* __restrict__ out) {
  int t = threadIdx.x, lane = t & 63, w = t >> 6;
  int fr = lane & 15, fg = lane >> 4;
  int n = blockIdx.x * 128 + w * 16 + fr;
  const float* wp = W + (size_t)n * DD + fg * 8;
  f32x4 acc[4];
  #pragma unroll
  for (int i = 0; i < 4; i++) acc[i] = (f32x4){0.f, 0.f, 0.f, 0.f};
  for (int k0 = 0; k0 < DD; k0 += 32) {
    float4 f0 = *reinterpret_cast<const float4*>(wp + k0);
    float4 f1 = *reinterpret_cast<const float4*>(wp + k0 + 4);
    U8 bfr;
    bfr.u[0] = pkbf(f0.x, f0.y); bfr.u[1] = pkbf(f0.z, f0.w);
    bfr.u[2] = pkbf(f1.x, f1.y); bfr.u[3] = pkbf(f1.z, f1.w);
    #pragma unroll
    for (int i = 0; i < 4; i++) {
      bf16x8 af = *reinterpret_cast<const bf16x8*>(POOL + (size_t)(i * 16 + fr) * DD + k0 + fg * 8);
      acc[i] = MFMA(af, bfr.v, acc[i], 0, 0, 0);
    }
  }
  float bs = bias[n];
  #pragma unroll
  for (int i = 0; i < 4; i++)
    #pragma unroll
    for (int r = 0; r < 4; r++)
      out[(size_t)(i * 16 + fg * 4 + r) * VV + n] = acc[i][r] + bs;
}

extern "C" void kernel_launch(void* const* d_in, const int* in_sizes, int n_in,
                              void* d_out, int out_size, void* d_ws, size_t ws_size,
                              hipStream_t stream) {
  const int*   tokens  = (const int*)d_in[0];
  const float* tok_emb = (const float*)d_in[2];
  const float* pos_emb = (const float*)d_in[3];
  const float* emb_g   = (const float*)d_in[4];
  const float* emb_b   = (const float*)d_in[5];
  const float* ln1_g   = (const float*)d_in[6];
  const float* ln1_b   = (const float*)d_in[7];
  const float* Wqkv    = (const float*)d_in[8];
  const float* bqkv    = (const float*)d_in[9];
  const float* Wo      = (const float*)d_in[10];
  const float* bo      = (const float*)d_in[11];
  const float* ln2_g   = (const float*)d_in[12];
  const float* ln2_b   = (const float*)d_in[13];
  const float* W1      = (const float*)d_in[14];
  const float* b1      = (const float*)d_in[15];
  const float* W2      = (const float*)d_in[16];
  const float* b2      = (const float*)d_in[17];
  const float* cls_W   = (const float*)d_in[22];
  const float* cls_b   = (const float*)d_in[23];

  char* ws = (char*)d_ws;
  float*    X    = (float*)ws;                         // 33,554,432 B
  ushort_t* QKV  = (ushort_t*)(ws + 33554432);         // 50,331,648 B (QKV / FF1)
  ushort_t* Hb   = (ushort_t*)(ws + 83886080);         // 16,777,216 B
  ushort_t* WB   = (ushort_t*)(ws + 100663296);        //  1,048,576 B per-layer weights bf16
  ushort_t* POOL = (ushort_t*)(ws + 101711872);        //     32,768 B
  int*      LEN  = (int*)(ws + 101744640);             //        256 B

  const int OFF_QKV = 0, OFF_WO = 196608, OFF_W1 = 262144, OFF_W2 = 393216;

  k_lens<<<BB, 256, 0, stream>>>(tokens, LEN);
  k_embed4<<<MM / 4, 256, 0, stream>>>(tokens, tok_emb, pos_emb, emb_g, emb_b, X);

  for (int e = 0; e < KK; e++) {
    k_cvtw<<<512, 256, 0, stream>>>(Wqkv + (size_t)e * 196608, Wo + (size_t)e * 65536,
                                    W1 + (size_t)e * 131072, W2 + (size_t)e * 131072, WB);
    k_ln4<<<MM / 4, 256, 0, stream>>>(X, ln1_g + e * DD, ln1_b + e * DD, LEN, (bf16*)Hb);
    k_mgemm<false, false, true><<<dim3(6, 256), 256, 0, stream>>>(
        Hb, WB + OFF_QKV, bqkv + e * 3 * DD, nullptr, QKV, LEN, MM, 3 * DD, DD);
    k_mattn2<<<dim3(4, HH, BB), 512, 0, stream>>>(QKV, LEN, Hb);
    k_mgemm<false, true, false><<<dim3(2, 256), 256, 0, stream>>>(
        Hb, WB + OFF_WO, bo + e * DD, X, X, LEN, MM, DD, DD);
    k_ln4<<<MM / 4, 256, 0, stream>>>(X, ln2_g + e * DD, ln2_b + e * DD, LEN, (bf16*)Hb);
    k_mgemm<true, false, true><<<dim3(4, 256), 256, 0, stream>>>(
        Hb, WB + OFF_W1, b1 + e * FF, nullptr, QKV, LEN, MM, FF, DD);
    k_mgemm<false, true, false><<<dim3(2, 256), 256, 0, stream>>>(
        QKV, WB + OFF_W2, b2 + e * DD, X, X, LEN, MM, DD, FF);
  }

  k_pool<<<BB, 256, 0, stream>>>(X, LEN, (bf16*)POOL);
  k_cls<<<dim3(VV / 128), 512, 0, stream>>>(POOL, cls_W, cls_b, (float*)d_out);
}